// Round 5
// baseline (1719.655 us; speedup 1.0000x reference)
//
#include <hip/hip_runtime.h>
#include <math.h>

#define IN_C  512
#define HID   256
#define OUT_C 32
#define GAMMA 0.25f   // 1/(1+lam2), lam2=3
#define BETA  2.0f    // 1/(2*gamma)
#define LAM1  3.0f
#define ZS    10922.0f        // int16 scale: 3*ZS = 32766 <= 32767
#define ZSI   (1.0f / 10922.0f)

// ---------------------------------------------------------------------------
// GEMM1: h1 = relu(x @ W1 + b1)   [M,512] x [512,256] -> [M,256], fp32 vector
// ---------------------------------------------------------------------------
#define BM 128
#define BN 128
#define BK 16

__global__ __launch_bounds__(256) void gemm1_relu_kernel(
    const float* __restrict__ A, const float* __restrict__ B,
    const float* __restrict__ bias, float* __restrict__ C, int M)
{
    __shared__ float As[BK][BM + 4];
    __shared__ float Bs[BK][BN + 4];
    const int tid = threadIdx.x;
    const int bm = blockIdx.x * BM;
    const int bn = blockIdx.y * BN;
    const int tx = tid & 15;
    const int ty = tid >> 4;

    float acc[8][8];
#pragma unroll
    for (int i = 0; i < 8; ++i)
#pragma unroll
        for (int j = 0; j < 8; ++j) acc[i][j] = 0.f;

    const int a_row = tid >> 2;
    const int a_col = (tid & 3) << 2;
    const int b_row = tid >> 5;
    const int b_col = (tid & 31) << 2;

    for (int k0 = 0; k0 < IN_C; k0 += BK) {
#pragma unroll
        for (int r = 0; r < 2; ++r) {
            const int m = a_row + r * 64;
            const int gm = bm + m;
            float4 v = make_float4(0.f, 0.f, 0.f, 0.f);
            if (gm < M) v = *(const float4*)&A[(size_t)gm * IN_C + k0 + a_col];
            As[a_col + 0][m] = v.x;
            As[a_col + 1][m] = v.y;
            As[a_col + 2][m] = v.z;
            As[a_col + 3][m] = v.w;
        }
#pragma unroll
        for (int r = 0; r < 2; ++r) {
            const int kk = b_row + r * 8;
            *(float4*)&Bs[kk][b_col] =
                *(const float4*)&B[(size_t)(k0 + kk) * HID + bn + b_col];
        }
        __syncthreads();
#pragma unroll
        for (int kk = 0; kk < BK; ++kk) {
            float a[8], b[8];
            *(float4*)&a[0] = *(float4*)&As[kk][ty * 8];
            *(float4*)&a[4] = *(float4*)&As[kk][ty * 8 + 4];
            *(float4*)&b[0] = *(float4*)&Bs[kk][tx * 4];
            *(float4*)&b[4] = *(float4*)&Bs[kk][64 + tx * 4];
#pragma unroll
            for (int i = 0; i < 8; ++i)
#pragma unroll
                for (int j = 0; j < 8; ++j)
                    acc[i][j] = fmaf(a[i], b[j], acc[i][j]);
        }
        __syncthreads();
    }

#pragma unroll
    for (int i = 0; i < 8; ++i) {
        const int gm = bm + ty * 8 + i;
        if (gm >= M) continue;
#pragma unroll
        for (int g = 0; g < 2; ++g) {
            const int gn = bn + g * 64 + tx * 4;
            float4 v;
            v.x = fmaxf(acc[i][g * 4 + 0] + bias[gn + 0], 0.f);
            v.y = fmaxf(acc[i][g * 4 + 1] + bias[gn + 1], 0.f);
            v.z = fmaxf(acc[i][g * 4 + 2] + bias[gn + 2], 0.f);
            v.w = fmaxf(acc[i][g * 4 + 3] + bias[gn + 3], 0.f);
            *(float4*)&C[(size_t)gm * HID + gn] = v;
        }
    }
}

// ---------------------------------------------------------------------------
// GEMM2: h = h1 @ W2 + b2; also y0 = gamma*h.  [M,256] x [256,32] -> [M,32]
// ---------------------------------------------------------------------------
#define G2_ROWS 128
#define G2_KT   64

__global__ __launch_bounds__(256) void gemm2_kernel(
    const float* __restrict__ H1, const float* __restrict__ W2,
    const float* __restrict__ b2, float* __restrict__ H,
    float* __restrict__ Y, int M)
{
    __shared__ float W2s[HID * OUT_C];
    __shared__ float rows_s[G2_ROWS][G2_KT + 4];
    const int tid = threadIdx.x;
    const int brow = blockIdx.x * G2_ROWS;
    const int cg = tid & 7;
    const int rg = tid >> 3;

#pragma unroll
    for (int r = 0; r < 8; ++r)
        ((float4*)W2s)[tid + r * 256] = ((const float4*)W2)[tid + r * 256];

    float acc[4][4];
#pragma unroll
    for (int r = 0; r < 4; ++r)
#pragma unroll
        for (int c = 0; c < 4; ++c) acc[r][c] = 0.f;

    for (int k0 = 0; k0 < HID; k0 += G2_KT) {
        __syncthreads();
#pragma unroll
        for (int i = 0; i < 8; ++i) {
            const int idx = tid + i * 256;
            const int rl = idx >> 4;
            const int c4 = idx & 15;
            const int gr = brow + rl;
            float4 v = make_float4(0.f, 0.f, 0.f, 0.f);
            if (gr < M) v = *(const float4*)&H1[(size_t)gr * HID + k0 + c4 * 4];
            *(float4*)&rows_s[rl][c4 * 4] = v;
        }
        __syncthreads();
#pragma unroll
        for (int kq = 0; kq < G2_KT / 4; ++kq) {
            float4 w[4];
#pragma unroll
            for (int j = 0; j < 4; ++j)
                w[j] = ((const float4*)W2s)[(k0 + kq * 4 + j) * 8 + cg];
#pragma unroll
            for (int r = 0; r < 4; ++r) {
                const float4 rh = *(const float4*)&rows_s[rg * 4 + r][kq * 4];
                acc[r][0] = fmaf(rh.x, w[0].x, acc[r][0]);
                acc[r][1] = fmaf(rh.x, w[0].y, acc[r][1]);
                acc[r][2] = fmaf(rh.x, w[0].z, acc[r][2]);
                acc[r][3] = fmaf(rh.x, w[0].w, acc[r][3]);
                acc[r][0] = fmaf(rh.y, w[1].x, acc[r][0]);
                acc[r][1] = fmaf(rh.y, w[1].y, acc[r][1]);
                acc[r][2] = fmaf(rh.y, w[1].z, acc[r][2]);
                acc[r][3] = fmaf(rh.y, w[1].w, acc[r][3]);
                acc[r][0] = fmaf(rh.z, w[2].x, acc[r][0]);
                acc[r][1] = fmaf(rh.z, w[2].y, acc[r][1]);
                acc[r][2] = fmaf(rh.z, w[2].z, acc[r][2]);
                acc[r][3] = fmaf(rh.z, w[2].w, acc[r][3]);
                acc[r][0] = fmaf(rh.w, w[3].x, acc[r][0]);
                acc[r][1] = fmaf(rh.w, w[3].y, acc[r][1]);
                acc[r][2] = fmaf(rh.w, w[3].z, acc[r][2]);
                acc[r][3] = fmaf(rh.w, w[3].w, acc[r][3]);
            }
        }
    }

    const float4 bias = *(const float4*)&b2[cg * 4];
#pragma unroll
    for (int r = 0; r < 4; ++r) {
        const int grow = brow + rg * 4 + r;
        if (grow >= M) continue;
        float4 s;
        s.x = acc[r][0] + bias.x;
        s.y = acc[r][1] + bias.y;
        s.z = acc[r][2] + bias.z;
        s.w = acc[r][3] + bias.w;
        *(float4*)&H[(size_t)grow * OUT_C + cg * 4] = s;
        float4 y0;
        y0.x = GAMMA * s.x; y0.y = GAMMA * s.y;
        y0.z = GAMMA * s.z; y0.w = GAMMA * s.w;
        *(float4*)&Y[(size_t)grow * OUT_C + cg * 4] = y0;
    }
}

// ---------------------------------------------------------------------------
// Preprocess: per-side histograms -> scans -> scatter.
// Row-CSR: edge e (renumbered) lives at its row-sorted position; col_s[e] is
// the col endpoint. Col-CSR: position p holds row_s[p] = row endpoint.
// z is stored TWICE (zr row-sorted, zc col-sorted); each side maintains its
// own copy in place -> all z traffic is contiguous, no double-buffer needed.
// ---------------------------------------------------------------------------
__global__ void hist2_kernel(const int* __restrict__ row, const int* __restrict__ col,
                             int* __restrict__ cnt_r, int* __restrict__ cnt_c, int E)
{
    const int t = blockIdx.x * blockDim.x + threadIdx.x;
    if (t >= E) return;
    atomicAdd(&cnt_r[row[t]], 1);
    atomicAdd(&cnt_c[col[t]], 1);
}

__global__ void dis_kernel(const int* __restrict__ cnt_r, const int* __restrict__ cnt_c,
                           float* __restrict__ dis, int N)
{
    const int t = blockIdx.x * blockDim.x + threadIdx.x;
    if (t < N) dis[t] = 1.f / sqrtf(fmaxf((float)(cnt_r[t] + cnt_c[t]), 1.f));
}

#define SCAN_CHUNK 1024

__global__ __launch_bounds__(256) void scan1_kernel(
    const int* __restrict__ counts, int* __restrict__ bsum, int N)
{
    __shared__ int sm[256];
    const int tid = threadIdx.x;
    const int base = blockIdx.x * SCAN_CHUNK + tid * 4;
    int s = 0;
#pragma unroll
    for (int i = 0; i < 4; ++i)
        if (base + i < N) s += counts[base + i];
    sm[tid] = s;
    __syncthreads();
    for (int off = 128; off; off >>= 1) {
        if (tid < off) sm[tid] += sm[tid + off];
        __syncthreads();
    }
    if (tid == 0) bsum[blockIdx.x] = sm[0];
}

__global__ void scan2_kernel(int* __restrict__ bsum, int* __restrict__ boff, int nb)
{
    if (threadIdx.x == 0 && blockIdx.x == 0) {
        int acc = 0;
        for (int i = 0; i < nb; ++i) { boff[i] = acc; acc += bsum[i]; }
    }
}

__global__ __launch_bounds__(256) void scan3_kernel(
    const int* __restrict__ counts, const int* __restrict__ boff,
    int* __restrict__ ptr, int* __restrict__ cursor, int N)
{
    __shared__ int sm[256];
    const int tid = threadIdx.x;
    const int base = blockIdx.x * SCAN_CHUNK + tid * 4;
    int c[4];
#pragma unroll
    for (int i = 0; i < 4; ++i)
        c[i] = (base + i < N) ? counts[base + i] : 0;
    const int tsum = c[0] + c[1] + c[2] + c[3];
    sm[tid] = tsum;
    __syncthreads();
    for (int off = 1; off < 256; off <<= 1) {
        int v = (tid >= off) ? sm[tid - off] : 0;
        __syncthreads();
        sm[tid] += v;
        __syncthreads();
    }
    int run = boff[blockIdx.x] + sm[tid] - tsum;  // exclusive
#pragma unroll
    for (int i = 0; i < 4; ++i) {
        if (base + i < N) {
            ptr[base + i] = run;
            cursor[base + i] = run;
        }
        run += c[i];
    }
}

__global__ void scatter2_kernel(const int* __restrict__ row, const int* __restrict__ col,
                                int* __restrict__ cur_r, int* __restrict__ cur_c,
                                int* __restrict__ col_s, int* __restrict__ row_s, int E)
{
    const int t = blockIdx.x * blockDim.x + threadIdx.x;
    if (t >= E) return;
    const int r = row[t], c = col[t];
    const int nid = atomicAdd(&cur_r[r], 1);    // row-CSR slot
    col_s[nid] = c;
    const int pc = atomicAdd(&cur_c[c], 1);     // col-CSR slot
    row_s[pc] = r;
}

// ---------------------------------------------------------------------------
// Fused EMP iteration, dual-sorted z, in-place.
// 8 threads/node (4 channels each). Both sides: contiguous z read/write,
// y gathered via adjacency (12.8 MB, cache-resident).
// ---------------------------------------------------------------------------
__device__ __forceinline__ float clip1(float v)
{
    return fminf(fmaxf(v, -LAM1), LAM1);
}

__device__ __forceinline__ float4 zload4(const short* p)
{
    const short4 s = *(const short4*)p;
    return make_float4(s.x * ZSI, s.y * ZSI, s.z * ZSI, s.w * ZSI);
}

__device__ __forceinline__ void zstore4(short* p, float4 z)
{
    short4 s;
    s.x = (short)__float2int_rn(z.x * ZS);
    s.y = (short)__float2int_rn(z.y * ZS);
    s.z = (short)__float2int_rn(z.z * ZS);
    s.w = (short)__float2int_rn(z.w * ZS);
    *(short4*)p = s;
}

template <bool FIRST, bool LAST>
__global__ __launch_bounds__(256) void emp_kernel(
    const int* __restrict__ rowptr, const int* __restrict__ cnt_r,
    const int* __restrict__ col_s,
    const int* __restrict__ colptr, const int* __restrict__ cnt_c,
    const int* __restrict__ row_s,
    short* __restrict__ zr, short* __restrict__ zc,
    const float* __restrict__ dis, const float* __restrict__ H,
    const float* __restrict__ Yold, float* __restrict__ Ynew,
    float* __restrict__ OUT, int N)
{
    const int t = blockIdx.x * 256 + threadIdx.x;
    const int n = t >> 3;
    if (n >= N) return;
    const int c4 = (t & 7) << 2;
    const float dn = dis[n];
    const float4 ys = *(const float4*)&Yold[(size_t)n * OUT_C + c4];
    const float4 ysdn = make_float4(ys.x * dn, ys.y * dn, ys.z * dn, ys.w * dn);

    float4 acc = make_float4(0.f, 0.f, 0.f, 0.f);

    // ---- row side: contiguous slots [rowptr[n], +cnt_r[n])
    {
        const int b = rowptr[n];
        const int d = cnt_r[n];
        for (int i = 0; i < d; ++i) {
            const int e = b + i;
            const int other = col_s[e];
            const float dt = dis[other];
            const float4 yo = *(const float4*)&Yold[(size_t)other * OUT_C + c4];
            float4 z;
            if (FIRST) z = make_float4(0.f, 0.f, 0.f, 0.f);
            else       z = zload4(&zr[(size_t)e * OUT_C + c4]);
            z.x = clip1(z.x + BETA * (ysdn.x - yo.x * dt));
            z.y = clip1(z.y + BETA * (ysdn.y - yo.y * dt));
            z.z = clip1(z.z + BETA * (ysdn.z - yo.z * dt));
            z.w = clip1(z.w + BETA * (ysdn.w - yo.w * dt));
            acc.x += z.x; acc.y += z.y; acc.z += z.z; acc.w += z.w;
            if (!LAST) zstore4(&zr[(size_t)e * OUT_C + c4], z);
        }
    }

    // ---- col side: contiguous slots [colptr[n], +cnt_c[n]) in zc
    {
        const int b = colptr[n];
        const int d = cnt_c[n];
        for (int i = 0; i < d; ++i) {
            const int p = b + i;
            const int other = row_s[p];
            const float dt = dis[other];
            const float4 yo = *(const float4*)&Yold[(size_t)other * OUT_C + c4];
            float4 z;
            if (FIRST) z = make_float4(0.f, 0.f, 0.f, 0.f);
            else       z = zload4(&zc[(size_t)p * OUT_C + c4]);
            z.x = clip1(z.x + BETA * (yo.x * dt - ysdn.x));
            z.y = clip1(z.y + BETA * (yo.y * dt - ysdn.y));
            z.z = clip1(z.z + BETA * (yo.z * dt - ysdn.z));
            z.w = clip1(z.w + BETA * (yo.w * dt - ysdn.w));
            acc.x -= z.x; acc.y -= z.y; acc.z -= z.z; acc.w -= z.w;
            if (!LAST) zstore4(&zc[(size_t)p * OUT_C + c4], z);
        }
    }

    const float4 h4 = *(const float4*)&H[(size_t)n * OUT_C + c4];
    float4 v;
    v.x = GAMMA * (h4.x - dn * acc.x);
    v.y = GAMMA * (h4.y - dn * acc.y);
    v.z = GAMMA * (h4.z - dn * acc.z);
    v.w = GAMMA * (h4.w - dn * acc.w);

    if (!LAST) {
        *(float4*)&Ynew[(size_t)n * OUT_C + c4] = v;
    } else {
        float m = fmaxf(fmaxf(v.x, v.y), fmaxf(v.z, v.w));
#pragma unroll
        for (int off = 4; off; off >>= 1) m = fmaxf(m, __shfl_xor(m, off, 8));
        float sum = expf(v.x - m) + expf(v.y - m) + expf(v.z - m) + expf(v.w - m);
#pragma unroll
        for (int off = 4; off; off >>= 1) sum += __shfl_xor(sum, off, 8);
        const float lse = m + logf(sum);
        float4 o;
        o.x = v.x - lse; o.y = v.y - lse; o.z = v.z - lse; o.w = v.w - lse;
        *(float4*)&OUT[(size_t)n * OUT_C + c4] = o;
    }
}

// ---------------------------------------------------------------------------
extern "C" void kernel_launch(void* const* d_in, const int* in_sizes, int n_in,
                              void* d_out, int out_size, void* d_ws, size_t ws_size,
                              hipStream_t stream)
{
    const float* x  = (const float*)d_in[0];
    const int*   ei = (const int*)d_in[1];   // [2,E] int32
    const float* W1 = (const float*)d_in[2];
    const float* b1 = (const float*)d_in[3];
    const float* W2 = (const float*)d_in[4];
    const float* b2 = (const float*)d_in[5];
    const int M = in_sizes[0] / IN_C;        // 100000
    const int E = in_sizes[1] / 2;           // 1600000
    const int* row = ei;
    const int* col = ei + E;

    // workspace layout (~260 MB):
    //   zr, zc: int16 [E,32] (102.4 MB each, in-place across iterations)
    //   h1 (fp32 M*HID = 102.4 MB) aliases zr: dead after gemm2, zr first
    //   written by emp iter 0 (FIRST skips z reads).
    char* ws = (char*)d_ws;
    short* zr = (short*)ws;
    short* zc = zr + (size_t)E * OUT_C;
    float* h1 = (float*)ws;                               // alias over zr
    float* h  = (float*)(zc + (size_t)E * OUT_C);
    float* y0 = h  + (size_t)M * OUT_C;
    float* y1 = y0 + (size_t)M * OUT_C;
    int* cnt_r   = (int*)(y1 + (size_t)M * OUT_C);
    int* cnt_c   = cnt_r + M;
    int* rowptr  = cnt_c + M;
    int* colptr  = rowptr + M;
    int* cur_r   = colptr + M;
    int* cur_c   = cur_r + M;
    float* dis   = (float*)(cur_c + M);
    const int nb = (M + SCAN_CHUNK - 1) / SCAN_CHUNK;
    int* bsum    = (int*)(dis + M);
    int* boff    = bsum + nb;
    int* col_s   = boff + nb;                             // E ints
    int* row_s   = col_s + E;                             // E ints

    hipMemsetAsync(cnt_r, 0, 2 * (size_t)M * sizeof(int), stream);

    // MLP
    dim3 g1((M + BM - 1) / BM, HID / BN);
    gemm1_relu_kernel<<<g1, 256, 0, stream>>>(x, W1, b1, h1, M);
    gemm2_kernel<<<(M + G2_ROWS - 1) / G2_ROWS, 256, 0, stream>>>(h1, W2, b2, h, y0, M);

    // CSR build + edge renumbering (both sorts)
    hist2_kernel<<<(E + 255) / 256, 256, 0, stream>>>(row, col, cnt_r, cnt_c, E);
    dis_kernel<<<(M + 255) / 256, 256, 0, stream>>>(cnt_r, cnt_c, dis, M);
    scan1_kernel<<<nb, 256, 0, stream>>>(cnt_r, bsum, M);
    scan2_kernel<<<1, 64, 0, stream>>>(bsum, boff, nb);
    scan3_kernel<<<nb, 256, 0, stream>>>(cnt_r, boff, rowptr, cur_r, M);
    scan1_kernel<<<nb, 256, 0, stream>>>(cnt_c, bsum, M);
    scan2_kernel<<<1, 64, 0, stream>>>(bsum, boff, nb);
    scan3_kernel<<<nb, 256, 0, stream>>>(cnt_c, boff, colptr, cur_c, M);
    scatter2_kernel<<<(E + 255) / 256, 256, 0, stream>>>(row, col, cur_r, cur_c,
                                                         col_s, row_s, E);

    // K = 5 fused EMP iterations (z in-place; y ping-pong 0->1->0->1->0->OUT)
    const int nblocks = (M * 8 + 255) / 256;
    emp_kernel<true, false><<<nblocks, 256, 0, stream>>>(
        rowptr, cnt_r, col_s, colptr, cnt_c, row_s,
        zr, zc, dis, h, y0, y1, nullptr, M);
    emp_kernel<false, false><<<nblocks, 256, 0, stream>>>(
        rowptr, cnt_r, col_s, colptr, cnt_c, row_s,
        zr, zc, dis, h, y1, y0, nullptr, M);
    emp_kernel<false, false><<<nblocks, 256, 0, stream>>>(
        rowptr, cnt_r, col_s, colptr, cnt_c, row_s,
        zr, zc, dis, h, y0, y1, nullptr, M);
    emp_kernel<false, false><<<nblocks, 256, 0, stream>>>(
        rowptr, cnt_r, col_s, colptr, cnt_c, row_s,
        zr, zc, dis, h, y1, y0, nullptr, M);
    emp_kernel<false, true><<<nblocks, 256, 0, stream>>>(
        rowptr, cnt_r, col_s, colptr, cnt_c, row_s,
        zr, zc, dis, h, y0, nullptr, (float*)d_out, M);
}

// Round 6
// 1668.037 us; speedup vs baseline: 1.0309x; 1.0309x over previous
//
#include <hip/hip_runtime.h>
#include <math.h>

#define IN_C  512
#define HID   256
#define OUT_C 32
#define GAMMA 0.25f   // 1/(1+lam2), lam2=3
#define BETA  2.0f    // 1/(2*gamma)
#define LAM1  3.0f
#define ZS    10922.0f        // int16 scale: 3*ZS = 32766 <= 32767
#define ZSI   (1.0f / 10922.0f)

// ---------------------------------------------------------------------------
// bf16 helpers (RNE), manual to avoid header semantics questions
// ---------------------------------------------------------------------------
__device__ __forceinline__ unsigned short f2bf(float f)
{
    unsigned u = __float_as_uint(f);
    return (unsigned short)((u + 0x7fffu + ((u >> 16) & 1u)) >> 16);
}
__device__ __forceinline__ float bf2f(unsigned short h)
{
    return __uint_as_float(((unsigned)h) << 16);
}

// ---------------------------------------------------------------------------
// W1 pre-split: W1 [512][256] fp32 -> W1hT, W1lT [256][512] bf16 (transposed
// so the GEMM's B-operand k-run is contiguous).
// ---------------------------------------------------------------------------
__global__ __launch_bounds__(256) void wconv_kernel(
    const float* __restrict__ W1, unsigned short* __restrict__ WhT,
    unsigned short* __restrict__ WlT)
{
    const int t = blockIdx.x * 256 + threadIdx.x;   // 512*256 threads
    const int k = t >> 8;
    const int n = t & 255;
    const float w = W1[t];
    const unsigned short h = f2bf(w);
    const unsigned short l = f2bf(w - bf2f(h));
    WhT[n * 512 + k] = h;
    WlT[n * 512 + k] = l;
}

// ---------------------------------------------------------------------------
// GEMM1 via MFMA: h1 = relu(x @ W1 + b1), fp32 emulated as bf16 hi/lo split:
//   a*b ~= ah*bh + ah*bl + al*bh   (al*bl ~ 2^-18 rel, dropped)
// Tile 128x128, 256 threads = 4 waves (2x2 of 64x64), K-step 32.
// v_mfma_f32_16x16x32_bf16: A row=lane&15,k=(lane>>4)*8+j; D col=lane&15,
// row=(lane>>4)*4+reg  [m89-verified layouts].
// LDS pitch 40 bf16 (80B): frag reads land 2-way on banks (free).
// ---------------------------------------------------------------------------
typedef __attribute__((ext_vector_type(8))) short bf16x8;
typedef __attribute__((ext_vector_type(4))) float f32x4;

#define PITCH 40

__global__ __launch_bounds__(256) void gemm1_mfma_kernel(
    const float* __restrict__ X, const unsigned short* __restrict__ WhT,
    const unsigned short* __restrict__ WlT, const float* __restrict__ bias,
    float* __restrict__ C, int M)
{
    __shared__ __align__(16) unsigned short Ah[128 * PITCH];
    __shared__ __align__(16) unsigned short Al[128 * PITCH];
    __shared__ __align__(16) unsigned short Bh[128 * PITCH];
    __shared__ __align__(16) unsigned short Bl[128 * PITCH];

    const int tid = threadIdx.x;
    const int bm = blockIdx.x * 128;
    const int bn = blockIdx.y * 128;
    const int lane = tid & 63;
    const int wid = tid >> 6;
    const int wm = (wid >> 1) * 64;
    const int wn = (wid & 1) * 64;
    const int l16 = lane & 15;
    const int l4 = lane >> 4;

    f32x4 acc[4][4];
#pragma unroll
    for (int i = 0; i < 4; ++i)
#pragma unroll
        for (int j = 0; j < 4; ++j) acc[i][j] = (f32x4){0.f, 0.f, 0.f, 0.f};

    for (int k0 = 0; k0 < IN_C; k0 += 32) {
        // ---- stage A: 128 rows x 32 k fp32 -> hi/lo bf16 in LDS
#pragma unroll
        for (int p = 0; p < 4; ++p) {
            const int idx = tid + p * 256;        // 0..1023
            const int r = idx >> 3;               // 0..127
            const int f4 = idx & 7;               // float4 within 32-k row
            float4 v = make_float4(0.f, 0.f, 0.f, 0.f);
            if (bm + r < M)
                v = *(const float4*)&X[(size_t)(bm + r) * IN_C + k0 + f4 * 4];
            const unsigned short h0 = f2bf(v.x), h1 = f2bf(v.y),
                                 h2 = f2bf(v.z), h3 = f2bf(v.w);
            const unsigned short l0 = f2bf(v.x - bf2f(h0)),
                                 l1 = f2bf(v.y - bf2f(h1)),
                                 l2 = f2bf(v.z - bf2f(h2)),
                                 l3 = f2bf(v.w - bf2f(h3));
            *(short4*)&Ah[r * PITCH + f4 * 4] =
                make_short4((short)h0, (short)h1, (short)h2, (short)h3);
            *(short4*)&Al[r * PITCH + f4 * 4] =
                make_short4((short)l0, (short)l1, (short)l2, (short)l3);
        }
        // ---- stage B: 128 cols x 32 k bf16 (pre-split), 16B copies
#pragma unroll
        for (int p = 0; p < 2; ++p) {
            const int idx = tid + p * 256;        // 0..511
            const int r = idx >> 2;               // col 0..127
            const int ch = idx & 3;               // 8-elem chunk
            const size_t g = (size_t)(bn + r) * IN_C + k0 + ch * 8;
            *(int4*)&Bh[r * PITCH + ch * 8] = *(const int4*)&WhT[g];
            *(int4*)&Bl[r * PITCH + ch * 8] = *(const int4*)&WlT[g];
        }
        __syncthreads();

        bf16x8 ah[4], al[4];
#pragma unroll
        for (int i = 0; i < 4; ++i) {
            const int arow = wm + i * 16 + l16;
            ah[i] = *(const bf16x8*)&Ah[arow * PITCH + l4 * 8];
            al[i] = *(const bf16x8*)&Al[arow * PITCH + l4 * 8];
        }
#pragma unroll
        for (int j = 0; j < 4; ++j) {
            const int bcol = wn + j * 16 + l16;
            const bf16x8 bh = *(const bf16x8*)&Bh[bcol * PITCH + l4 * 8];
            const bf16x8 bl = *(const bf16x8*)&Bl[bcol * PITCH + l4 * 8];
#pragma unroll
            for (int i = 0; i < 4; ++i) {
                acc[i][j] = __builtin_amdgcn_mfma_f32_16x16x32_bf16(
                    ah[i], bh, acc[i][j], 0, 0, 0);
                acc[i][j] = __builtin_amdgcn_mfma_f32_16x16x32_bf16(
                    ah[i], bl, acc[i][j], 0, 0, 0);
                acc[i][j] = __builtin_amdgcn_mfma_f32_16x16x32_bf16(
                    al[i], bh, acc[i][j], 0, 0, 0);
            }
        }
        __syncthreads();
    }

    // ---- epilogue: bias + relu, D layout col=lane&15, row=(lane>>4)*4+reg
#pragma unroll
    for (int j = 0; j < 4; ++j) {
        const int col = bn + wn + j * 16 + l16;
        const float bv = bias[col];
#pragma unroll
        for (int i = 0; i < 4; ++i) {
#pragma unroll
            for (int r = 0; r < 4; ++r) {
                const int row = bm + wm + i * 16 + l4 * 4 + r;
                if (row < M)
                    C[(size_t)row * HID + col] = fmaxf(acc[i][j][r] + bv, 0.f);
            }
        }
    }
}

// ---------------------------------------------------------------------------
// GEMM2: h = h1 @ W2 + b2; also y0 = gamma*h.  [M,256] x [256,32] -> [M,32]
// ---------------------------------------------------------------------------
#define G2_ROWS 128
#define G2_KT   64

__global__ __launch_bounds__(256) void gemm2_kernel(
    const float* __restrict__ H1, const float* __restrict__ W2,
    const float* __restrict__ b2, float* __restrict__ H,
    float* __restrict__ Y, int M)
{
    __shared__ float W2s[HID * OUT_C];
    __shared__ float rows_s[G2_ROWS][G2_KT + 4];
    const int tid = threadIdx.x;
    const int brow = blockIdx.x * G2_ROWS;
    const int cg = tid & 7;
    const int rg = tid >> 3;

#pragma unroll
    for (int r = 0; r < 8; ++r)
        ((float4*)W2s)[tid + r * 256] = ((const float4*)W2)[tid + r * 256];

    float acc[4][4];
#pragma unroll
    for (int r = 0; r < 4; ++r)
#pragma unroll
        for (int c = 0; c < 4; ++c) acc[r][c] = 0.f;

    for (int k0 = 0; k0 < HID; k0 += G2_KT) {
        __syncthreads();
#pragma unroll
        for (int i = 0; i < 8; ++i) {
            const int idx = tid + i * 256;
            const int rl = idx >> 4;
            const int c4 = idx & 15;
            const int gr = brow + rl;
            float4 v = make_float4(0.f, 0.f, 0.f, 0.f);
            if (gr < M) v = *(const float4*)&H1[(size_t)gr * HID + k0 + c4 * 4];
            *(float4*)&rows_s[rl][c4 * 4] = v;
        }
        __syncthreads();
#pragma unroll
        for (int kq = 0; kq < G2_KT / 4; ++kq) {
            float4 w[4];
#pragma unroll
            for (int j = 0; j < 4; ++j)
                w[j] = ((const float4*)W2s)[(k0 + kq * 4 + j) * 8 + cg];
#pragma unroll
            for (int r = 0; r < 4; ++r) {
                const float4 rh = *(const float4*)&rows_s[rg * 4 + r][kq * 4];
                acc[r][0] = fmaf(rh.x, w[0].x, acc[r][0]);
                acc[r][1] = fmaf(rh.x, w[0].y, acc[r][1]);
                acc[r][2] = fmaf(rh.x, w[0].z, acc[r][2]);
                acc[r][3] = fmaf(rh.x, w[0].w, acc[r][3]);
                acc[r][0] = fmaf(rh.y, w[1].x, acc[r][0]);
                acc[r][1] = fmaf(rh.y, w[1].y, acc[r][1]);
                acc[r][2] = fmaf(rh.y, w[1].z, acc[r][2]);
                acc[r][3] = fmaf(rh.y, w[1].w, acc[r][3]);
                acc[r][0] = fmaf(rh.z, w[2].x, acc[r][0]);
                acc[r][1] = fmaf(rh.z, w[2].y, acc[r][1]);
                acc[r][2] = fmaf(rh.z, w[2].z, acc[r][2]);
                acc[r][3] = fmaf(rh.z, w[2].w, acc[r][3]);
                acc[r][0] = fmaf(rh.w, w[3].x, acc[r][0]);
                acc[r][1] = fmaf(rh.w, w[3].y, acc[r][1]);
                acc[r][2] = fmaf(rh.w, w[3].z, acc[r][2]);
                acc[r][3] = fmaf(rh.w, w[3].w, acc[r][3]);
            }
        }
    }

    const float4 bias = *(const float4*)&b2[cg * 4];
#pragma unroll
    for (int r = 0; r < 4; ++r) {
        const int grow = brow + rg * 4 + r;
        if (grow >= M) continue;
        float4 s;
        s.x = acc[r][0] + bias.x;
        s.y = acc[r][1] + bias.y;
        s.z = acc[r][2] + bias.z;
        s.w = acc[r][3] + bias.w;
        *(float4*)&H[(size_t)grow * OUT_C + cg * 4] = s;
        float4 y0;
        y0.x = GAMMA * s.x; y0.y = GAMMA * s.y;
        y0.z = GAMMA * s.z; y0.w = GAMMA * s.w;
        *(float4*)&Y[(size_t)grow * OUT_C + cg * 4] = y0;
    }
}

// ---------------------------------------------------------------------------
// Preprocess: per-side histograms -> scans -> scatter (dual CSR).
// ---------------------------------------------------------------------------
__global__ void hist2_kernel(const int* __restrict__ row, const int* __restrict__ col,
                             int* __restrict__ cnt_r, int* __restrict__ cnt_c, int E)
{
    const int t = blockIdx.x * blockDim.x + threadIdx.x;
    if (t >= E) return;
    atomicAdd(&cnt_r[row[t]], 1);
    atomicAdd(&cnt_c[col[t]], 1);
}

__global__ void dis_kernel(const int* __restrict__ cnt_r, const int* __restrict__ cnt_c,
                           float* __restrict__ dis, int N)
{
    const int t = blockIdx.x * blockDim.x + threadIdx.x;
    if (t < N) dis[t] = 1.f / sqrtf(fmaxf((float)(cnt_r[t] + cnt_c[t]), 1.f));
}

#define SCAN_CHUNK 1024

__global__ __launch_bounds__(256) void scan1_kernel(
    const int* __restrict__ counts, int* __restrict__ bsum, int N)
{
    __shared__ int sm[256];
    const int tid = threadIdx.x;
    const int base = blockIdx.x * SCAN_CHUNK + tid * 4;
    int s = 0;
#pragma unroll
    for (int i = 0; i < 4; ++i)
        if (base + i < N) s += counts[base + i];
    sm[tid] = s;
    __syncthreads();
    for (int off = 128; off; off >>= 1) {
        if (tid < off) sm[tid] += sm[tid + off];
        __syncthreads();
    }
    if (tid == 0) bsum[blockIdx.x] = sm[0];
}

__global__ void scan2_kernel(int* __restrict__ bsum, int* __restrict__ boff, int nb)
{
    if (threadIdx.x == 0 && blockIdx.x == 0) {
        int acc = 0;
        for (int i = 0; i < nb; ++i) { boff[i] = acc; acc += bsum[i]; }
    }
}

__global__ __launch_bounds__(256) void scan3_kernel(
    const int* __restrict__ counts, const int* __restrict__ boff,
    int* __restrict__ ptr, int* __restrict__ cursor, int N)
{
    __shared__ int sm[256];
    const int tid = threadIdx.x;
    const int base = blockIdx.x * SCAN_CHUNK + tid * 4;
    int c[4];
#pragma unroll
    for (int i = 0; i < 4; ++i)
        c[i] = (base + i < N) ? counts[base + i] : 0;
    const int tsum = c[0] + c[1] + c[2] + c[3];
    sm[tid] = tsum;
    __syncthreads();
    for (int off = 1; off < 256; off <<= 1) {
        int v = (tid >= off) ? sm[tid - off] : 0;
        __syncthreads();
        sm[tid] += v;
        __syncthreads();
    }
    int run = boff[blockIdx.x] + sm[tid] - tsum;  // exclusive
#pragma unroll
    for (int i = 0; i < 4; ++i) {
        if (base + i < N) {
            ptr[base + i] = run;
            cursor[base + i] = run;
        }
        run += c[i];
    }
}

__global__ void scatter2_kernel(const int* __restrict__ row, const int* __restrict__ col,
                                int* __restrict__ cur_r, int* __restrict__ cur_c,
                                int* __restrict__ col_s, int* __restrict__ row_s, int E)
{
    const int t = blockIdx.x * blockDim.x + threadIdx.x;
    if (t >= E) return;
    const int r = row[t], c = col[t];
    const int nid = atomicAdd(&cur_r[r], 1);    // row-CSR slot
    col_s[nid] = c;
    const int pc = atomicAdd(&cur_c[c], 1);     // col-CSR slot
    row_s[pc] = r;
}

// ---------------------------------------------------------------------------
// Fused EMP iteration, dual-sorted z, in-place. 8 threads/node.
// ---------------------------------------------------------------------------
__device__ __forceinline__ float clip1(float v)
{
    return fminf(fmaxf(v, -LAM1), LAM1);
}

__device__ __forceinline__ float4 zload4(const short* p)
{
    const short4 s = *(const short4*)p;
    return make_float4(s.x * ZSI, s.y * ZSI, s.z * ZSI, s.w * ZSI);
}

__device__ __forceinline__ void zstore4(short* p, float4 z)
{
    short4 s;
    s.x = (short)__float2int_rn(z.x * ZS);
    s.y = (short)__float2int_rn(z.y * ZS);
    s.z = (short)__float2int_rn(z.z * ZS);
    s.w = (short)__float2int_rn(z.w * ZS);
    *(short4*)p = s;
}

template <bool FIRST, bool LAST>
__global__ __launch_bounds__(256) void emp_kernel(
    const int* __restrict__ rowptr, const int* __restrict__ cnt_r,
    const int* __restrict__ col_s,
    const int* __restrict__ colptr, const int* __restrict__ cnt_c,
    const int* __restrict__ row_s,
    short* __restrict__ zr, short* __restrict__ zc,
    const float* __restrict__ dis, const float* __restrict__ H,
    const float* __restrict__ Yold, float* __restrict__ Ynew,
    float* __restrict__ OUT, int N)
{
    const int t = blockIdx.x * 256 + threadIdx.x;
    const int n = t >> 3;
    if (n >= N) return;
    const int c4 = (t & 7) << 2;
    const float dn = dis[n];
    const float4 ys = *(const float4*)&Yold[(size_t)n * OUT_C + c4];
    const float4 ysdn = make_float4(ys.x * dn, ys.y * dn, ys.z * dn, ys.w * dn);

    float4 acc = make_float4(0.f, 0.f, 0.f, 0.f);

    // ---- row side: contiguous slots [rowptr[n], +cnt_r[n])
    {
        const int b = rowptr[n];
        const int d = cnt_r[n];
        for (int i = 0; i < d; ++i) {
            const int e = b + i;
            const int other = col_s[e];
            const float dt = dis[other];
            const float4 yo = *(const float4*)&Yold[(size_t)other * OUT_C + c4];
            float4 z;
            if (FIRST) z = make_float4(0.f, 0.f, 0.f, 0.f);
            else       z = zload4(&zr[(size_t)e * OUT_C + c4]);
            z.x = clip1(z.x + BETA * (ysdn.x - yo.x * dt));
            z.y = clip1(z.y + BETA * (ysdn.y - yo.y * dt));
            z.z = clip1(z.z + BETA * (ysdn.z - yo.z * dt));
            z.w = clip1(z.w + BETA * (ysdn.w - yo.w * dt));
            acc.x += z.x; acc.y += z.y; acc.z += z.z; acc.w += z.w;
            if (!LAST) zstore4(&zr[(size_t)e * OUT_C + c4], z);
        }
    }

    // ---- col side: contiguous slots [colptr[n], +cnt_c[n]) in zc
    {
        const int b = colptr[n];
        const int d = cnt_c[n];
        for (int i = 0; i < d; ++i) {
            const int p = b + i;
            const int other = row_s[p];
            const float dt = dis[other];
            const float4 yo = *(const float4*)&Yold[(size_t)other * OUT_C + c4];
            float4 z;
            if (FIRST) z = make_float4(0.f, 0.f, 0.f, 0.f);
            else       z = zload4(&zc[(size_t)p * OUT_C + c4]);
            z.x = clip1(z.x + BETA * (yo.x * dt - ysdn.x));
            z.y = clip1(z.y + BETA * (yo.y * dt - ysdn.y));
            z.z = clip1(z.z + BETA * (yo.z * dt - ysdn.z));
            z.w = clip1(z.w + BETA * (yo.w * dt - ysdn.w));
            acc.x -= z.x; acc.y -= z.y; acc.z -= z.z; acc.w -= z.w;
            if (!LAST) zstore4(&zc[(size_t)p * OUT_C + c4], z);
        }
    }

    const float4 h4 = *(const float4*)&H[(size_t)n * OUT_C + c4];
    float4 v;
    v.x = GAMMA * (h4.x - dn * acc.x);
    v.y = GAMMA * (h4.y - dn * acc.y);
    v.z = GAMMA * (h4.z - dn * acc.z);
    v.w = GAMMA * (h4.w - dn * acc.w);

    if (!LAST) {
        *(float4*)&Ynew[(size_t)n * OUT_C + c4] = v;
    } else {
        float m = fmaxf(fmaxf(v.x, v.y), fmaxf(v.z, v.w));
#pragma unroll
        for (int off = 4; off; off >>= 1) m = fmaxf(m, __shfl_xor(m, off, 8));
        float sum = expf(v.x - m) + expf(v.y - m) + expf(v.z - m) + expf(v.w - m);
#pragma unroll
        for (int off = 4; off; off >>= 1) sum += __shfl_xor(sum, off, 8);
        const float lse = m + logf(sum);
        float4 o;
        o.x = v.x - lse; o.y = v.y - lse; o.z = v.z - lse; o.w = v.w - lse;
        *(float4*)&OUT[(size_t)n * OUT_C + c4] = o;
    }
}

// ---------------------------------------------------------------------------
extern "C" void kernel_launch(void* const* d_in, const int* in_sizes, int n_in,
                              void* d_out, int out_size, void* d_ws, size_t ws_size,
                              hipStream_t stream)
{
    const float* x  = (const float*)d_in[0];
    const int*   ei = (const int*)d_in[1];   // [2,E] int32
    const float* W1 = (const float*)d_in[2];
    const float* b1 = (const float*)d_in[3];
    const float* W2 = (const float*)d_in[4];
    const float* b2 = (const float*)d_in[5];
    const int M = in_sizes[0] / IN_C;        // 100000
    const int E = in_sizes[1] / 2;           // 1600000
    const int* row = ei;
    const int* col = ei + E;

    // workspace layout (~248 MB):
    //   zr, zc: int16 [E,32] (102.4 MB each, in-place across iterations)
    //   h1 (fp32 M*HID = 102.4 MB) aliases zr (dead after gemm2)
    char* ws = (char*)d_ws;
    short* zr = (short*)ws;
    short* zc = zr + (size_t)E * OUT_C;
    float* h1 = (float*)ws;                               // alias over zr
    float* h  = (float*)(zc + (size_t)E * OUT_C);
    float* y0 = h  + (size_t)M * OUT_C;
    float* y1 = y0 + (size_t)M * OUT_C;
    int* cnt_r   = (int*)(y1 + (size_t)M * OUT_C);
    int* cnt_c   = cnt_r + M;
    int* rowptr  = cnt_c + M;
    int* colptr  = rowptr + M;
    int* cur_r   = colptr + M;
    int* cur_c   = cur_r + M;
    float* dis   = (float*)(cur_c + M);
    const int nb = (M + SCAN_CHUNK - 1) / SCAN_CHUNK;
    int* bsum    = (int*)(dis + M);
    int* boff    = bsum + nb;
    int* col_s   = boff + nb;                             // E ints
    int* row_s   = col_s + E;                             // E ints
    unsigned short* W1hT = (unsigned short*)(row_s + E);  // 256*512 bf16
    unsigned short* W1lT = W1hT + HID * IN_C;

    hipMemsetAsync(cnt_r, 0, 2 * (size_t)M * sizeof(int), stream);

    // MLP: W split + MFMA gemm1, then fp32 gemm2
    wconv_kernel<<<IN_C, 256, 0, stream>>>(W1, W1hT, W1lT);
    dim3 g1((M + 127) / 128, HID / 128);
    gemm1_mfma_kernel<<<g1, 256, 0, stream>>>(x, W1hT, W1lT, b1, h1, M);
    gemm2_kernel<<<(M + G2_ROWS - 1) / G2_ROWS, 256, 0, stream>>>(h1, W2, b2, h, y0, M);

    // CSR build + edge renumbering (both sorts)
    hist2_kernel<<<(E + 255) / 256, 256, 0, stream>>>(row, col, cnt_r, cnt_c, E);
    dis_kernel<<<(M + 255) / 256, 256, 0, stream>>>(cnt_r, cnt_c, dis, M);
    scan1_kernel<<<nb, 256, 0, stream>>>(cnt_r, bsum, M);
    scan2_kernel<<<1, 64, 0, stream>>>(bsum, boff, nb);
    scan3_kernel<<<nb, 256, 0, stream>>>(cnt_r, boff, rowptr, cur_r, M);
    scan1_kernel<<<nb, 256, 0, stream>>>(cnt_c, bsum, M);
    scan2_kernel<<<1, 64, 0, stream>>>(bsum, boff, nb);
    scan3_kernel<<<nb, 256, 0, stream>>>(cnt_c, boff, colptr, cur_c, M);
    scatter2_kernel<<<(E + 255) / 256, 256, 0, stream>>>(row, col, cur_r, cur_c,
                                                         col_s, row_s, E);

    // K = 5 fused EMP iterations (z in-place; y ping-pong 0->1->0->1->0->OUT)
    const int nblocks = (M * 8 + 255) / 256;
    emp_kernel<true, false><<<nblocks, 256, 0, stream>>>(
        rowptr, cnt_r, col_s, colptr, cnt_c, row_s,
        zr, zc, dis, h, y0, y1, nullptr, M);
    emp_kernel<false, false><<<nblocks, 256, 0, stream>>>(
        rowptr, cnt_r, col_s, colptr, cnt_c, row_s,
        zr, zc, dis, h, y1, y0, nullptr, M);
    emp_kernel<false, false><<<nblocks, 256, 0, stream>>>(
        rowptr, cnt_r, col_s, colptr, cnt_c, row_s,
        zr, zc, dis, h, y0, y1, nullptr, M);
    emp_kernel<false, false><<<nblocks, 256, 0, stream>>>(
        rowptr, cnt_r, col_s, colptr, cnt_c, row_s,
        zr, zc, dis, h, y1, y0, nullptr, M);
    emp_kernel<false, true><<<nblocks, 256, 0, stream>>>(
        rowptr, cnt_r, col_s, colptr, cnt_c, row_s,
        zr, zc, dis, h, y0, nullptr, (float*)d_out, M);
}